// Round 1
// baseline (1571.131 us; speedup 1.0000x reference)
//
#include <hip/hip_runtime.h>
#include <hip/hip_bf16.h>

#define D 128
#define KTOP 3
#define NCLS 10
#define EPS 1e-5f
#define BM 64

// ---------------- degree / CSR build ----------------

__global__ void deg_kernel(const int* __restrict__ src, const int* __restrict__ dst,
                           int* __restrict__ deg_out, int* __restrict__ deg_in, int E) {
    int e = blockIdx.x * blockDim.x + threadIdx.x;
    if (e >= E) return;
    atomicAdd(&deg_out[src[e]], 1);
    atomicAdd(&deg_in[dst[e]], 1);
}

__global__ void rs_kernel(const int* __restrict__ deg_out, const int* __restrict__ deg_in,
                          float* __restrict__ rs_out, float* __restrict__ rs_in, int N) {
    int i = blockIdx.x * blockDim.x + threadIdx.x;
    if (i >= N) return;
    int a = deg_out[i]; if (a < 1) a = 1;
    int b = deg_in[i];  if (b < 1) b = 1;
    rs_out[i] = rsqrtf((float)a);
    rs_in[i]  = rsqrtf((float)b);
}

// single-block exclusive scan of deg_in -> offs[0..N], offs[N]=E
__global__ __launch_bounds__(1024) void scan_kernel(const int* __restrict__ deg,
                                                    int* __restrict__ offs, int N) {
    __shared__ int part[1024];
    int t = threadIdx.x;
    int per = (N + 1023) >> 10;
    int beg = t * per;
    int end = beg + per; if (end > N) end = N;
    int s = 0;
    for (int i = beg; i < end; ++i) s += deg[i];
    part[t] = s;
    __syncthreads();
    for (int off = 1; off < 1024; off <<= 1) {
        int v = (t >= off) ? part[t - off] : 0;
        __syncthreads();
        part[t] += v;
        __syncthreads();
    }
    int run = (t == 0) ? 0 : part[t - 1];
    for (int i = beg; i < end; ++i) { offs[i] = run; run += deg[i]; }
    if (t == 1023) offs[N] = run;
}

__global__ void csr_scatter(const int* __restrict__ src, const int* __restrict__ dst,
                            const int* __restrict__ offs, int* __restrict__ cursor,
                            int* __restrict__ csr, int E) {
    int e = blockIdx.x * blockDim.x + threadIdx.x;
    if (e >= E) return;
    int d = dst[e];
    int pos = offs[d] + atomicAdd(&cursor[d], 1);
    csr[pos] = src[e];
}

// ---------------- aggregation: one wave per dst node ----------------

__global__ __launch_bounds__(256) void aggregate_kernel(const float* __restrict__ hin,
        const int* __restrict__ offs, const int* __restrict__ csr,
        const float* __restrict__ rs_out, const float* __restrict__ rs_in,
        float* __restrict__ hout, int N) {
    int wv   = (blockIdx.x * 256 + threadIdx.x) >> 6;
    int lane = threadIdx.x & 63;
    if (wv >= N) return;
    int beg = offs[wv], end = offs[wv + 1];
    float ax = 0.f, ay = 0.f;
    for (int e = beg; e < end; ++e) {
        int s = csr[e];
        float w = rs_out[s];
        float2 v = *reinterpret_cast<const float2*>(hin + (size_t)s * D + lane * 2);
        ax += w * v.x;
        ay += w * v.y;
    }
    float ri = rs_in[wv];
    float2 r; r.x = ax * ri; r.y = ay * ri;
    *reinterpret_cast<float2*>(hout + (size_t)wv * D + lane * 2) = r;
}

// ---------------- in-place GEMM: h[64 rows] = h[64 rows] @ W + b ----------------
// Block owns BM=64 rows and ALL 128 output cols -> reads exactly the rows it
// writes (staged fully in LDS before any write) => in-place safe across blocks.

__global__ __launch_bounds__(256) void gemm_bias_inplace(float* __restrict__ h,
        const float* __restrict__ W, const float* __restrict__ bias, int N) {
    __shared__ __align__(16) float At[D][BM + 4];  // A transposed [k][m], padded
    __shared__ __align__(16) float Wl[32][D];      // W chunk [k][c]
    int t = threadIdx.x;
    size_t rowBase = (size_t)blockIdx.x * BM;

    // stage A transposed: thread reads 4 rows at column kk, writes float4 At[kk][m4..]
    for (int i = t; i < D * (BM / 4); i += 256) {
        int kk = i & (D - 1);
        int m4 = (i >> 7) << 2;
        float4 v;
        v.x = h[(rowBase + m4 + 0) * D + kk];
        v.y = h[(rowBase + m4 + 1) * D + kk];
        v.z = h[(rowBase + m4 + 2) * D + kk];
        v.w = h[(rowBase + m4 + 3) * D + kk];
        *reinterpret_cast<float4*>(&At[kk][m4]) = v;
    }

    int tx = t & 15, ty = t >> 4;
    int r0 = tx * 4, c0 = ty * 8;
    float acc[4][8];
#pragma unroll
    for (int i = 0; i < 4; ++i)
#pragma unroll
        for (int j = 0; j < 8; ++j) acc[i][j] = 0.f;

    for (int kc = 0; kc < D; kc += 32) {
        __syncthreads();
        // stage W chunk [kc..kc+32) x 128
        const float4* Wv = reinterpret_cast<const float4*>(W + (size_t)kc * D);
        float4* Wd = reinterpret_cast<float4*>(&Wl[0][0]);
        for (int i = t; i < 32 * D / 4; i += 256) Wd[i] = Wv[i];
        __syncthreads();
#pragma unroll 8
        for (int k = 0; k < 32; ++k) {
            float4 a  = *reinterpret_cast<const float4*>(&At[kc + k][r0]);
            float4 w0 = *reinterpret_cast<const float4*>(&Wl[k][c0]);
            float4 w1 = *reinterpret_cast<const float4*>(&Wl[k][c0 + 4]);
            float av[4] = {a.x, a.y, a.z, a.w};
            float wv[8] = {w0.x, w0.y, w0.z, w0.w, w1.x, w1.y, w1.z, w1.w};
#pragma unroll
            for (int i = 0; i < 4; ++i)
#pragma unroll
                for (int j = 0; j < 8; ++j) acc[i][j] += av[i] * wv[j];
        }
    }

    float4 b0 = *reinterpret_cast<const float4*>(&bias[c0]);
    float4 b1 = *reinterpret_cast<const float4*>(&bias[c0 + 4]);
#pragma unroll
    for (int i = 0; i < 4; ++i) {
        size_t row = rowBase + r0 + i;
        float4 o0, o1;
        o0.x = acc[i][0] + b0.x; o0.y = acc[i][1] + b0.y;
        o0.z = acc[i][2] + b0.z; o0.w = acc[i][3] + b0.w;
        o1.x = acc[i][4] + b1.x; o1.y = acc[i][5] + b1.y;
        o1.z = acc[i][6] + b1.z; o1.w = acc[i][7] + b1.w;
        *reinterpret_cast<float4*>(&h[row * D + c0])     = o0;
        *reinterpret_cast<float4*>(&h[row * D + c0 + 4]) = o1;
    }
}

// ---------------- BatchNorm ----------------

__global__ __launch_bounds__(256) void bn_stats(const float* __restrict__ h,
                                                float* __restrict__ sums, int N) {
    int c = threadIdx.x & (D - 1);
    int half = threadIdx.x >> 7;
    float s = 0.f, s2 = 0.f;
    for (int r = blockIdx.x * 2 + half; r < N; r += gridDim.x * 2) {
        float v = h[(size_t)r * D + c];
        s += v; s2 += v * v;
    }
    atomicAdd(&sums[c], s);
    atomicAdd(&sums[D + c], s2);
}

__global__ void bn_final(const float* __restrict__ sums, const float* __restrict__ g,
                         const float* __restrict__ bt, float* __restrict__ sc,
                         float* __restrict__ sh, int N) {
    int c = threadIdx.x;
    if (c >= D) return;
    float mu  = sums[c] / (float)N;
    float var = sums[D + c] / (float)N - mu * mu;
    float inv = rsqrtf(var + EPS);
    float scale = g[c] * inv;
    sc[c] = scale;
    sh[c] = bt[c] - mu * scale;
}

__global__ __launch_bounds__(256) void bn_apply_relu_max(float* __restrict__ h,
        const float* __restrict__ sc, const float* __restrict__ sh,
        float* __restrict__ nodemax, int N) {
    int wv   = (blockIdx.x * 256 + threadIdx.x) >> 6;
    int lane = threadIdx.x & 63;
    if (wv >= N) return;
    float2 v = *reinterpret_cast<const float2*>(h + (size_t)wv * D + lane * 2);
    float2 a = *reinterpret_cast<const float2*>(sc + lane * 2);
    float2 b = *reinterpret_cast<const float2*>(sh + lane * 2);
    float x = fmaxf(v.x * a.x + b.x, 0.f);
    float y = fmaxf(v.y * a.y + b.y, 0.f);
    float2 o; o.x = x; o.y = y;
    *reinterpret_cast<float2*>(h + (size_t)wv * D + lane * 2) = o;
    float m = fmaxf(x, y);
#pragma unroll
    for (int d = 32; d > 0; d >>= 1) m = fmaxf(m, __shfl_down(m, d, 64));
    if (lane == 0) nodemax[wv] = m;
}

__global__ __launch_bounds__(256) void rowmax_kernel(const float* __restrict__ h,
                                                     float* __restrict__ nodemax, int N) {
    int wv   = (blockIdx.x * 256 + threadIdx.x) >> 6;
    int lane = threadIdx.x & 63;
    if (wv >= N) return;
    float2 v = *reinterpret_cast<const float2*>(h + (size_t)wv * D + lane * 2);
    float m = fmaxf(v.x, v.y);
#pragma unroll
    for (int d = 32; d > 0; d >>= 1) m = fmaxf(m, __shfl_down(m, d, 64));
    if (lane == 0) nodemax[wv] = m;
}

// ---------------- SortPool top-k + head ----------------

__global__ void topk_kernel(const float* __restrict__ nodemax, int* __restrict__ tk,
                            int G, int NPG) {
    int g = blockIdx.x * blockDim.x + threadIdx.x;
    if (g >= G) return;
    const float* nm = nodemax + (size_t)g * NPG;
    float v0 = -3.4e38f, v1 = -3.4e38f, v2 = -3.4e38f;
    int i0 = 0, i1 = 0, i2 = 0;
    for (int j = 0; j < NPG; ++j) {
        float v = nm[j];
        if (v > v2) {
            if (v > v0)      { v2 = v1; i2 = i1; v1 = v0; i1 = i0; v0 = v; i0 = j; }
            else if (v > v1) { v2 = v1; i2 = i1; v1 = v;  i1 = j; }
            else             { v2 = v;  i2 = j; }
        }
    }
    tk[g * 3 + 0] = g * NPG + i0;
    tk[g * 3 + 1] = g * NPG + i1;
    tk[g * 3 + 2] = g * NPG + i2;
}

__global__ void score_init(float* __restrict__ score, const float* __restrict__ b0,
                           const float* __restrict__ b1, const float* __restrict__ b2,
                           const float* __restrict__ b3, int G) {
    int i = blockIdx.x * blockDim.x + threadIdx.x;
    if (i >= G * NCLS) return;
    int c = i % NCLS;
    score[i] = b0[c] + b1[c] + b2[c] + b3[c];
}

// one block (128 thr) per (graph, k): sort node features asc, dot with Pw rows
__global__ __launch_bounds__(128) void sort_head(const float* __restrict__ h,
        const int* __restrict__ tk, const float* __restrict__ Pw,
        float* __restrict__ score, int G) {
    int b = blockIdx.x;
    int g = b / KTOP, k = b - g * KTOP;
    int node = tk[b];
    int t = threadIdx.x;
    __shared__ float s[D];
    __shared__ float red[2][NCLS];
    s[t] = h[(size_t)node * D + t];
    __syncthreads();
    for (int size = 2; size <= D; size <<= 1) {
        for (int stride = size >> 1; stride > 0; stride >>= 1) {
            int ixj = t ^ stride;
            if (ixj > t) {
                float a = s[t], c = s[ixj];
                bool up = ((t & size) == 0);
                if ((a > c) == up) { s[t] = c; s[ixj] = a; }
            }
            __syncthreads();
        }
    }
    float v = s[t];
    const float* pw = Pw + (size_t)(k * D + t) * NCLS;
    float part[NCLS];
#pragma unroll
    for (int c = 0; c < NCLS; ++c) part[c] = v * pw[c];
    int lane = t & 63, wid = t >> 6;
#pragma unroll
    for (int c = 0; c < NCLS; ++c) {
        float x = part[c];
#pragma unroll
        for (int o = 32; o > 0; o >>= 1) x += __shfl_down(x, o, 64);
        if (lane == 0) red[wid][c] = x;
    }
    __syncthreads();
    if (t < NCLS) atomicAdd(&score[g * NCLS + t], red[0][t] + red[1][t]);
}

// ---------------- launch ----------------

extern "C" void kernel_launch(void* const* d_in, const int* in_sizes, int n_in,
                              void* d_out, int out_size, void* d_ws, size_t ws_size,
                              hipStream_t stream) {
    const float* x   = (const float*)d_in[0];
    const int*   src = (const int*)d_in[1];
    const int*   dst = (const int*)d_in[2];
    const float* W[3]  = {(const float*)d_in[5],  (const float*)d_in[9],  (const float*)d_in[13]};
    const float* bb[3] = {(const float*)d_in[6],  (const float*)d_in[10], (const float*)d_in[14]};
    const float* gg[3] = {(const float*)d_in[7],  (const float*)d_in[11], (const float*)d_in[15]};
    const float* bt[3] = {(const float*)d_in[8],  (const float*)d_in[12], (const float*)d_in[16]};
    const float* Pw[4] = {(const float*)d_in[17], (const float*)d_in[19], (const float*)d_in[21], (const float*)d_in[23]};
    const float* Pb[4] = {(const float*)d_in[18], (const float*)d_in[20], (const float*)d_in[22], (const float*)d_in[24]};

    int N = in_sizes[0] / D;
    int E = in_sizes[1];
    int G = out_size / NCLS;
    int NPG = N / G;
    float* score = (float*)d_out;

    size_t NF = (size_t)N * D;
    float* fws     = (float*)d_ws;
    float* H       = fws;
    float* T       = H + NF;
    float* rs_out  = T + NF;
    float* rs_in   = rs_out + N;
    float* nodemax = rs_in + N;
    float* bnsums  = nodemax + N;      // 2*D
    float* bscale  = bnsums + 2 * D;   // D
    float* bshift  = bscale + D;       // D
    int* deg_out = (int*)(bshift + D);
    int* deg_in  = deg_out + N;
    int* cursor  = deg_in + N;
    int* offs    = cursor + N;         // N+1
    int* csr     = offs + N + 1;       // E
    int* tk      = csr + E;            // G*3

    // degrees + CSR (graph is static but must be rebuilt deterministically per call)
    hipMemsetAsync(deg_out, 0, sizeof(int) * (size_t)3 * N, stream);  // deg_out, deg_in, cursor
    deg_kernel<<<(E + 255) / 256, 256, 0, stream>>>(src, dst, deg_out, deg_in, E);
    rs_kernel<<<(N + 255) / 256, 256, 0, stream>>>(deg_out, deg_in, rs_out, rs_in, N);
    scan_kernel<<<1, 1024, 0, stream>>>(deg_in, offs, N);
    csr_scatter<<<(E + 255) / 256, 256, 0, stream>>>(src, dst, offs, cursor, csr, E);

    score_init<<<(G * NCLS + 255) / 256, 256, 0, stream>>>(score, Pb[0], Pb[1], Pb[2], Pb[3], G);

    // rep 0 head (raw x)
    rowmax_kernel<<<N / 4, 256, 0, stream>>>(x, nodemax, N);
    topk_kernel<<<(G + 255) / 256, 256, 0, stream>>>(nodemax, tk, G, NPG);
    sort_head<<<G * KTOP, D, 0, stream>>>(x, tk, Pw[0], score, G);

    const float* hin = x;
    float* bufs[3] = {H, T, H};
    for (int l = 0; l < 3; ++l) {
        float* hout = bufs[l];
        aggregate_kernel<<<N / 4, 256, 0, stream>>>(hin, offs, csr, rs_out, rs_in, hout, N);
        gemm_bias_inplace<<<N / BM, 256, 0, stream>>>(hout, W[l], bb[l], N);
        hipMemsetAsync(bnsums, 0, sizeof(float) * 2 * D, stream);
        bn_stats<<<1024, 256, 0, stream>>>(hout, bnsums, N);
        bn_final<<<1, D, 0, stream>>>(bnsums, gg[l], bt[l], bscale, bshift, N);
        bn_apply_relu_max<<<N / 4, 256, 0, stream>>>(hout, bscale, bshift, nodemax, N);
        topk_kernel<<<(G + 255) / 256, 256, 0, stream>>>(nodemax, tk, G, NPG);
        sort_head<<<G * KTOP, D, 0, stream>>>(hout, tk, Pw[l + 1], score, G);
        hin = hout;
    }
}